// Round 3
// baseline (5244.080 us; speedup 1.0000x reference)
//
#include <hip/hip_runtime.h>
#include <stdint.h>

typedef __attribute__((ext_vector_type(8))) short bf16x8;
typedef __attribute__((ext_vector_type(4))) float f32x4;

#define DEV __device__ __forceinline__

DEV unsigned short f2bf(float f) {
    unsigned b = __float_as_uint(f);
    unsigned r = (b + 0x7fffu + ((b >> 16) & 1u)) >> 16;   // RNE
    return (unsigned short)r;
}
DEV unsigned pack2(float a, float b) {
    return (unsigned)f2bf(a) | ((unsigned)f2bf(b) << 16);
}
DEV float sigm(float x) { return 1.f / (1.f + __expf(-x)); }
DEV float tanh_f(float x) {
    float t = __expf(-2.f * fabsf(x));
    float r = (1.f - t) / (1.f + t);
    return copysignf(r, x);
}

// ws layout (bytes), total ~12.1 MB
#define OFF_HGLOB 8192       // 16 KB: 2 x 2048 u32 h double-buffer (A-frag order)
#define OFF_LSE   24576      // 16 KB fp32 lse[4096]
#define OFF_XE    65536      // 2 MB bf16 Xe[4096][256]
#define OFF_XG    2162688    // 8 MB bf16 xg[4096][1024]
#define OFF_HS    10551296   // 2 MB bf16 hs[4096][256]

// ---------------------------------------------------------------------------
// Embedding gather + fp32->bf16: Xe[row][0:200] = bf16(emb[x[row]]), pad 0
// ---------------------------------------------------------------------------
__global__ __launch_bounds__(256) void k_embed(const int* __restrict__ x,
                                               const float* __restrict__ emb,
                                               unsigned short* __restrict__ Xe)
{
    int row = blockIdx.x * 8 + (threadIdx.x >> 5);
    int i = threadIdx.x & 31;
    int tok = x[row];
    uint4 v = make_uint4(0, 0, 0, 0);
    if (i < 25) {
        const float* p = emb + (size_t)tok * 200 + i * 8;
        float4 f0 = *(const float4*)p;
        float4 f1 = *(const float4*)(p + 4);
        v.x = pack2(f0.x, f0.y); v.y = pack2(f0.z, f0.w);
        v.z = pack2(f1.x, f1.y); v.w = pack2(f1.z, f1.w);
    }
    *(uint4*)(Xe + (size_t)row * 256 + i * 8) = v;
}

// ---------------------------------------------------------------------------
// GEMM: OUT[M,N] = X[M,Kpad=256](bf16) @ W[N,K](fp32->bf16)^T + bias(fp32)
// block tile 128x128, 4 waves, wave = 64x64 (4x4 16x16x32 bf16 MFMA frags).
// X rows zero-padded past K. OUT_F32=1 -> fp32 outf, else bf16 outb.
// ---------------------------------------------------------------------------
template <int OUT_F32>
__global__ __launch_bounds__(256) void k_gemm(const unsigned short* __restrict__ X, int ldx,
                                              const float* __restrict__ W, int K,
                                              const float* __restrict__ bias,
                                              unsigned short* __restrict__ outb,
                                              float* __restrict__ outf, int N)
{
    __shared__ __align__(16) unsigned short Al[128 * 72];   // 64 cols + 8 pad
    __shared__ __align__(16) unsigned short Bl[128 * 72];
    const int tid = threadIdx.x, lane = tid & 63, wave = tid >> 6;
    const int wm = wave >> 1, wn = wave & 1;
    const int bm = blockIdx.y, bn = blockIdx.x;
    const int l15 = lane & 15, q = lane >> 4;

    f32x4 acc[4][4];
#pragma unroll
    for (int a = 0; a < 4; a++)
#pragma unroll
        for (int b = 0; b < 4; b++) acc[a][b] = f32x4{0.f, 0.f, 0.f, 0.f};

    for (int kb = 0; kb < 256; kb += 64) {
        __syncthreads();
#pragma unroll
        for (int it = 0; it < 4; ++it) {
            int p = tid + it * 256;            // 1024 chunks: 128 rows x 8 elems
            int row = p >> 3, c8 = p & 7;
            int col = kb + c8 * 8;
            uint4 av = *(const uint4*)(X + (size_t)(bm * 128 + row) * ldx + col);
            *(uint4*)(Al + row * 72 + c8 * 8) = av;
            uint4 bv = make_uint4(0, 0, 0, 0);
            if (col < K) {
                const float* wp = W + (size_t)(bn * 128 + row) * K + col;
                float4 f0 = *(const float4*)wp;
                float4 f1 = *(const float4*)(wp + 4);
                bv.x = pack2(f0.x, f0.y); bv.y = pack2(f0.z, f0.w);
                bv.z = pack2(f1.x, f1.y); bv.w = pack2(f1.z, f1.w);
            }
            *(uint4*)(Bl + row * 72 + c8 * 8) = bv;
        }
        __syncthreads();
#pragma unroll
        for (int kt = 0; kt < 2; ++kt) {
            bf16x8 a[4], b[4];
#pragma unroll
            for (int mt = 0; mt < 4; ++mt)
                a[mt] = *(const bf16x8*)(Al + (wm * 64 + mt * 16 + l15) * 72 + kt * 32 + q * 8);
#pragma unroll
            for (int nt = 0; nt < 4; ++nt)
                b[nt] = *(const bf16x8*)(Bl + (wn * 64 + nt * 16 + l15) * 72 + kt * 32 + q * 8);
#pragma unroll
            for (int mt = 0; mt < 4; ++mt)
#pragma unroll
                for (int nt = 0; nt < 4; ++nt)
                    acc[mt][nt] = __builtin_amdgcn_mfma_f32_16x16x32_bf16(a[mt], b[nt], acc[mt][nt], 0, 0, 0);
        }
    }
    // epilogue: D elem (m = q*4+r, n = l15) per 16x16 tile
#pragma unroll
    for (int nt = 0; nt < 4; ++nt) {
        int gn = bn * 128 + wn * 64 + nt * 16 + l15;
        float bv = bias[gn];
#pragma unroll
        for (int mt = 0; mt < 4; ++mt) {
#pragma unroll
            for (int r = 0; r < 4; ++r) {
                int gm = bm * 128 + wm * 64 + mt * 16 + q * 4 + r;
                float v = acc[mt][nt][r] + bv;
                if (OUT_F32) outf[(size_t)gm * N + gn] = v;
                else outb[(size_t)gm * N + gn] = f2bf(v);
            }
        }
    }
}

// ---------------------------------------------------------------------------
// LSTM recurrent scan, one layer. 16 WGs x 256 thr. WG s owns units
// [s*16,s*16+16) across all 4 gates; Wh slice (fp32->bf16) in LDS B-frag
// (32 KB). Per step: g[16b,64rows] = xg + h@Wh^T (MFMA M=16), cell update,
// h published via hglob (device-scope atomics) + monotonic progress flags.
// ---------------------------------------------------------------------------
__global__ __launch_bounds__(256) void k_scan(const float* __restrict__ Wh,           // [1024][256] fp32
                                              const unsigned short* __restrict__ xg,  // [4096][1024] bf16
                                              unsigned short* __restrict__ hseq,      // [4096][256] bf16
                                              unsigned* __restrict__ hglob,           // [2][2048] u32
                                              unsigned* __restrict__ prog)            // 16 slots, stride 32
{
    __shared__ __align__(16) unsigned short Wl[4 * 8 * 64 * 8];   // 32 KB [gate][kt][lane][8]
    __shared__ __align__(16) unsigned short hA[4096];             // 8 KB A-frag h[t-1]
    __shared__ float gbuf[64 * 17];
    __shared__ float hsh[16 * 17];
    const int tid = threadIdx.x, lane = tid & 63, wave = tid >> 6;
    const int s = blockIdx.x;
    const int l15 = lane & 15, q = lane >> 4;

    for (int p = tid; p < 2048; p += 256) {
        int nt = p >> 9, kt = (p >> 6) & 7, l = p & 63;
        int growp = nt * 256 + s * 16 + (l & 15);
        int k0 = kt * 32 + (l >> 4) * 8;
        const float* wp = Wh + (size_t)growp * 256 + k0;
        float4 f0 = *(const float4*)wp;
        float4 f1 = *(const float4*)(wp + 4);
        uint4 bv;
        bv.x = pack2(f0.x, f0.y); bv.y = pack2(f0.z, f0.w);
        bv.z = pack2(f1.x, f1.y); bv.w = pack2(f1.z, f1.w);
        *(uint4*)(Wl + ((nt * 8 + kt) * 64 + l) * 8) = bv;
    }
    const int eb = tid >> 4, eu = tid & 15;
    float c = 0.f;
    const int grow = wave * 256 + s * 16 + l15;   // this lane's gate-row
    __syncthreads();

    for (int t = 0; t < 256; ++t) {
        // prefetch xg (bf16) for C-init — independent of the spin
        float x0 = __uint_as_float(((unsigned)xg[(size_t)((q * 4 + 0) * 256 + t) * 1024 + grow]) << 16);
        float x1 = __uint_as_float(((unsigned)xg[(size_t)((q * 4 + 1) * 256 + t) * 1024 + grow]) << 16);
        float x2 = __uint_as_float(((unsigned)xg[(size_t)((q * 4 + 2) * 256 + t) * 1024 + grow]) << 16);
        float x3 = __uint_as_float(((unsigned)xg[(size_t)((q * 4 + 3) * 256 + t) * 1024 + grow]) << 16);

        unsigned* hA32 = (unsigned*)hA;
        if (t > 0) {
            if (tid < 16) {
                while (__hip_atomic_load(prog + tid * 32, __ATOMIC_ACQUIRE,
                                         __HIP_MEMORY_SCOPE_AGENT) < (unsigned)t) {}
            }
            __syncthreads();
            const unsigned* src = hglob + ((t - 1) & 1) * 2048;
#pragma unroll
            for (int i = 0; i < 8; ++i)
                hA32[tid + i * 256] =
                    __hip_atomic_load(src + tid + i * 256, __ATOMIC_RELAXED, __HIP_MEMORY_SCOPE_AGENT);
        } else {
#pragma unroll
            for (int i = 0; i < 8; ++i) hA32[tid + i * 256] = 0u;
        }
        __syncthreads();

        f32x4 acc = {x0, x1, x2, x3};
#pragma unroll
        for (int kt = 0; kt < 8; ++kt) {
            bf16x8 a = *(const bf16x8*)(hA + (kt * 64 + lane) * 8);
            bf16x8 b = *(const bf16x8*)(Wl + ((wave * 8 + kt) * 64 + lane) * 8);
            acc = __builtin_amdgcn_mfma_f32_16x16x32_bf16(a, b, acc, 0, 0, 0);
        }
        {
            int rowb = wave * 16 + l15;
#pragma unroll
            for (int r = 0; r < 4; ++r) gbuf[rowb * 17 + q * 4 + r] = acc[r];
        }
        __syncthreads();
        {
            float gi = gbuf[(0 * 16 + eu) * 17 + eb];
            float gf = gbuf[(1 * 16 + eu) * 17 + eb];
            float gg = gbuf[(2 * 16 + eu) * 17 + eb];
            float go = gbuf[(3 * 16 + eu) * 17 + eb];
            float i_ = sigm(gi), f_ = sigm(gf), g_ = tanh_f(gg), o_ = sigm(go);
            c = f_ * c + i_ * g_;
            hsh[eu * 17 + eb] = o_ * tanh_f(c);
        }
        __syncthreads();
        if (tid < 128) {   // pack unit pairs -> u32, publish
            int b = tid >> 3, ue = (tid & 7) * 2;
            unsigned pk = pack2(hsh[ue * 17 + b], hsh[(ue + 1) * 17 + b]);
            int ug = s * 16 + ue;
            int kt = ug >> 5, qq = (ug >> 3) & 3, j = ug & 7;
            unsigned idx = (unsigned)(((kt * 64 + qq * 16 + b) * 8 + j) >> 1);
            __hip_atomic_store(hglob + (t & 1) * 2048 + idx, pk, __ATOMIC_RELAXED,
                               __HIP_MEMORY_SCOPE_AGENT);
            *(unsigned*)(hseq + (size_t)(b * 256 + t) * 256 + ug) = pk;
        }
        __threadfence();
        __syncthreads();
        if (tid == 0)
            __hip_atomic_store(prog + s * 32, (unsigned)(t + 1), __ATOMIC_RELEASE,
                               __HIP_MEMORY_SCOPE_AGENT);
    }
}

// ---------------------------------------------------------------------------
// Per-row online logsumexp over V=32000 fp32 logits -> lse[row]
// ---------------------------------------------------------------------------
__global__ __launch_bounds__(256) void k_lse(const float* __restrict__ lg,
                                             float* __restrict__ lse)
{
    __shared__ float sm[8], ss[8];
    const int row = blockIdx.x, tid = threadIdx.x;
    const float* p = lg + (size_t)row * 32000;
    float m = -3.0e38f, s = 0.f;
    for (int i = tid; i < 4000; i += 256) {
        float4 f0 = *(const float4*)(p + i * 8);
        float4 f1 = *(const float4*)(p + i * 8 + 4);
        float v[8] = {f0.x, f0.y, f0.z, f0.w, f1.x, f1.y, f1.z, f1.w};
        float ml = v[0];
#pragma unroll
        for (int j = 1; j < 8; j++) ml = fmaxf(ml, v[j]);
        if (ml > m) { s *= __expf(m - ml); m = ml; }
        float a = 0.f;
#pragma unroll
        for (int j = 0; j < 8; j++) a += __expf(v[j] - m);
        s += a;
    }
#pragma unroll
    for (int off = 32; off; off >>= 1) {
        float m2 = __shfl_xor(m, off);
        float s2 = __shfl_xor(s, off);
        float nm = fmaxf(m, m2);
        s = s * __expf(m - nm) + s2 * __expf(m2 - nm);
        m = nm;
    }
    if ((tid & 63) == 0) { sm[tid >> 6] = m; ss[tid >> 6] = s; }
    __syncthreads();
    if (tid == 0) {
        float M = sm[0], S = ss[0];
        for (int w = 1; w < 4; ++w) {
            float m2 = sm[w], s2 = ss[w];
            float nm = fmaxf(M, m2);
            S = S * __expf(M - nm) + s2 * __expf(m2 - nm);
            M = nm;
        }
        lse[row] = M + __logf(S);
    }
}

__global__ __launch_bounds__(256) void k_sub(float* __restrict__ lg,
                                             const float* __restrict__ lse)
{
    const int row = blockIdx.y;
    const int i = blockIdx.x * 256 + threadIdx.x;
    if (i >= 4000) return;
    float* p = lg + (size_t)row * 32000 + i * 8;
    const float L = lse[row];
    float4 f0 = *(const float4*)p;
    float4 f1 = *(const float4*)(p + 4);
    f0.x -= L; f0.y -= L; f0.z -= L; f0.w -= L;
    f1.x -= L; f1.y -= L; f1.z -= L; f1.w -= L;
    *(float4*)p = f0;
    *(float4*)(p + 4) = f1;
}

// ---------------------------------------------------------------------------
extern "C" void kernel_launch(void* const* d_in, const int* in_sizes, int n_in,
                              void* d_out, int out_size, void* d_ws, size_t ws_size,
                              hipStream_t stream)
{
    const int* x = (const int*)d_in[0];
    const float* emb = (const float*)d_in[1];
    const float* Wi0 = (const float*)d_in[2];
    const float* Wh0 = (const float*)d_in[3];
    const float* b0  = (const float*)d_in[4];
    const float* Wi1 = (const float*)d_in[5];
    const float* Wh1 = (const float*)d_in[6];
    const float* b1  = (const float*)d_in[7];
    const float* Wi2 = (const float*)d_in[8];
    const float* Wh2 = (const float*)d_in[9];
    const float* b2  = (const float*)d_in[10];
    const float* fcW = (const float*)d_in[11];
    const float* fcb = (const float*)d_in[12];
    float* out = (float*)d_out;

    uint8_t* w = (uint8_t*)d_ws;
    unsigned* hglob = (unsigned*)(w + OFF_HGLOB);
    float* lse      = (float*)(w + OFF_LSE);
    unsigned short* Xe = (unsigned short*)(w + OFF_XE);
    unsigned short* xg = (unsigned short*)(w + OFF_XG);
    unsigned short* hs = (unsigned short*)(w + OFF_HS);

    hipMemsetAsync(w, 0, 8 * 1024, stream);   // zero progress flags (3 x 2048 B)

    k_embed<<<512, 256, 0, stream>>>(x, emb, Xe);

    k_gemm<0><<<dim3(8, 32), 256, 0, stream>>>(Xe, 256, Wi0, 200, b0, xg, nullptr, 1024);
    k_scan<<<16, 256, 0, stream>>>(Wh0, xg, hs, hglob, (unsigned*)(w + 0 * 2048));

    k_gemm<0><<<dim3(8, 32), 256, 0, stream>>>(hs, 256, Wi1, 256, b1, xg, nullptr, 1024);
    k_scan<<<16, 256, 0, stream>>>(Wh1, xg, hs, hglob, (unsigned*)(w + 1 * 2048));

    k_gemm<0><<<dim3(8, 32), 256, 0, stream>>>(hs, 256, Wi2, 256, b2, xg, nullptr, 1024);
    k_scan<<<16, 256, 0, stream>>>(Wh2, xg, hs, hglob, (unsigned*)(w + 2 * 2048));

    k_gemm<1><<<dim3(250, 32), 256, 0, stream>>>(hs, 256, fcW, 256, fcb, nullptr, out, 32000);

    k_lse<<<4096, 256, 0, stream>>>(out, lse);
    k_sub<<<dim3(16, 4096), 256, 0, stream>>>(out, lse);
}